// Round 2
// baseline (419.101 us; speedup 1.0000x reference)
//
#include <hip/hip_runtime.h>

#define N_NODES 50000
#define N_EDGES 800000

typedef short  bf16x8 __attribute__((ext_vector_type(8)));
typedef float  f32x4  __attribute__((ext_vector_type(4)));

// 64-bit fixed point (primary): scale 2^36.
//   quantization 2^-36 = 1.5e-11, range +-2^26 in value units -> bulletproof.
#define FXP64_SCALE 68719476736.0f             // 2^36
#define FXP64_INV   1.4551915228366852e-11     // 2^-36 (double)

// 32-bit fallback (only if ws too small): scale 2^22.
#define FXP32_SCALE 4194304.0f                 // 2^22
#define FXP32_INV   2.384185791015625e-07f     // 2^-22

#define ACC64_BYTES ((size_t)N_NODES * 40 * 8) // 16,000,000 B
#define WSB_BYTES   (36864 * 2)                // 73,728 B

__device__ __forceinline__ unsigned short f2bf(float f) {
    unsigned u = __float_as_uint(f);
    u += 0x7FFF + ((u >> 16) & 1);          // RNE
    return (unsigned short)(u >> 16);
}

// ---------------------------------------------------------------------------
// zero an int4 region (used for the i64 accumulator, or d_out in fallback)
// ---------------------------------------------------------------------------
__global__ void zero_kernel(int4* __restrict__ p, int n16) {
    int i = blockIdx.x * blockDim.x + threadIdx.x;
    if (i < n16) p[i] = make_int4(0, 0, 0, 0);
}

// ---------------------------------------------------------------------------
// finalize (64-bit path): acc (i64 fxp, in ws) -> d_out (f32). Separate
// buffers; fully overwrites d_out (harness poison handled here).
// ---------------------------------------------------------------------------
__global__ void finalize64_kernel(const long long* __restrict__ acc,
                                  float* __restrict__ out, int n) {
    int i = blockIdx.x * blockDim.x + threadIdx.x;
    if (i < n) out[i] = (float)((double)acc[i] * FXP64_INV);
}

// ---------------------------------------------------------------------------
// finalize (32-bit fallback): in-place int32 fxp -> float in d_out.
// NOTE: no __restrict__ — same buffer through both pointers.
// ---------------------------------------------------------------------------
__global__ void finalize32_kernel(int4* pi, float4* pf, int n4) {
    int i = blockIdx.x * blockDim.x + threadIdx.x;
    if (i < n4) {
        int4 v = pi[i];
        float4 f;
        f.x = (float)v.x * FXP32_INV;
        f.y = (float)v.y * FXP32_INV;
        f.z = (float)v.z * FXP32_INV;
        f.w = (float)v.w * FXP32_INV;
        pf[i] = f;
    }
}

// ---------------------------------------------------------------------------
// pack W2 (64x576 f32) into bf16 B-fragment order.
// B-frag for (nt, ks): lane L holds B[k = ks*32 + (L>>4)*8 + j][n = nt*16 + (L&15)],
// j = 0..7 contiguous. Flat index: ((nt*2+ks)*64 + L)*8 + j.
// ---------------------------------------------------------------------------
__global__ void prep_w2_kernel(const float* __restrict__ W2,
                               unsigned short* __restrict__ wsB) {
    int gid = blockIdx.x * 256 + threadIdx.x;      // 36864 total
    if (gid >= 36864) return;
    int j    = gid & 7;
    int lane = (gid >> 3) & 63;
    int ks   = (gid >> 9) & 1;
    int nt   = gid >> 10;
    int k = ks * 32 + (lane >> 4) * 8 + j;
    int n = nt * 16 + (lane & 15);
    wsB[gid] = f2bf(W2[k * 576 + n]);
}

// ---------------------------------------------------------------------------
// fused conv. Block = 256 = 4 independent waves; wave = 64 edges.
// MODE64=1: scatter via i64 fixed-point atomics into acc (ws).
// MODE64=0: scatter via i32 fixed-point atomics into d_out.
// Integer accumulation is associative+commutative and per-edge values are
// schedule-independent => output bitwise-deterministic (tripwire-safe).
// ---------------------------------------------------------------------------
template<int MODE64>
__global__ __launch_bounds__(256, 2) void conv_kernel(
    const float* __restrict__ pos,
    const float* __restrict__ f_in,
    const int*   __restrict__ esrc,
    const int*   __restrict__ edst,
    const float* __restrict__ W1,
    const unsigned short* __restrict__ wsB,
    void*        __restrict__ accPtr)
{
    // per-wave scratch, reused 3x:
    //   h-stage : 64 edges x 72 bf16 (stride-padded) = 9216 B
    //   w-tile  : 64 edges x 20 f32 (stride-padded)  = 5120 B
    //   out-tile: 64 edges x 44 f32 (stride-padded)  = 11264 B
    __shared__ __align__(16) char smem[4][11264];
    const int tid  = threadIdx.x;
    const int wave = tid >> 6;
    const int lane = tid & 63;
    const int e     = blockIdx.x * 256 + tid;
    const int wbase = blockIdx.x * 256 + wave * 64;
    char*  my  = smem[wave];
    float* shf = (float*)my;

    const int s = esrc[e];
    const int d = edst[e];

    // --- geometry -----------------------------------------------------------
    float px = pos[3*d+0] - pos[3*s+0];
    float py = pos[3*d+1] - pos[3*s+1];
    float pz = pos[3*d+2] - pos[3*s+2];
    float r  = sqrtf(px*px + py*py + pz*pz + 1e-12f);
    float inv_r = __builtin_amdgcn_rcpf(r);
    float ux = px*inv_r, uy = py*inv_r, uz = pz*inv_r;
    const float SQ3 = 1.7320508075688772f;
    float shx = SQ3*ux, shy = SQ3*uy, shz = SQ3*uz;

    // --- x = f_in[src] into VGPRs ------------------------------------------
    float x0[16], x1[24], dot[8];
    {
        const float4* xg4 = reinterpret_cast<const float4*>(f_in + (size_t)s * 40);
        float xr[40];
        #pragma unroll
        for (int q8 = 0; q8 < 10; ++q8) {
            float4 v = xg4[q8];
            xr[4*q8+0] = v.x; xr[4*q8+1] = v.y; xr[4*q8+2] = v.z; xr[4*q8+3] = v.w;
        }
        #pragma unroll
        for (int i = 0; i < 16; ++i) x0[i] = xr[i];
        #pragma unroll
        for (int i = 0; i < 24; ++i) x1[i] = xr[16+i];
        #pragma unroll
        for (int u = 0; u < 8; ++u)
            dot[u] = x1[3*u+0]*ux + x1[3*u+1]*uy + x1[3*u+2]*uz;  // = inv_s3*(x1.sh1)
    }

    // --- radial embedding ---------------------------------------------------
    const float A = 1.14136f * 7.38905609893065f;   // 1.14136 * e^2
    const float inv_step = 17.0f / 5.0f;
    float emb[16];
    #pragma unroll
    for (int k = 0; k < 16; ++k) {
        float dd  = r * inv_step - (float)(k + 1);
        float d2v = dd * dd;
        float arg = -2.0f * __builtin_amdgcn_rcpf(1.0f - d2v);
        float val = A * __expf(arg);
        emb[k] = (d2v < 1.0f) ? val : 0.0f;
    }

    // --- h = silu(emb @ W1) -------------------------------------------------
    float h[64];
    #pragma unroll
    for (int i = 0; i < 64; ++i) h[i] = 0.f;
    #pragma unroll
    for (int k = 0; k < 16; ++k) {
        const float ek = emb[k];
        const float* w1row = W1 + k * 64;
        #pragma unroll
        for (int i = 0; i < 64; ++i) h[i] = fmaf(ek, w1row[i], h[i]);
    }
    #pragma unroll
    for (int i = 0; i < 64; ++i) {
        float z = h[i];
        h[i] = z * __builtin_amdgcn_rcpf(1.0f + __expf(-z));
    }

    // --- stage h -> LDS in [edge][k] bf16, row stride 72 bf16 (144 B) ------
    {
        unsigned int hp[32];
        #pragma unroll
        for (int i = 0; i < 32; ++i)
            hp[i] = (unsigned)f2bf(h[2*i]) | ((unsigned)f2bf(h[2*i+1]) << 16);
        uint4* hrow = (uint4*)(my + lane * 144);
        #pragma unroll
        for (int g = 0; g < 8; ++g)
            hrow[g] = make_uint4(hp[4*g], hp[4*g+1], hp[4*g+2], hp[4*g+3]);
    }
    asm volatile("s_waitcnt lgkmcnt(0)" ::: "memory");

    // --- load A fragments (then h-region is dead, aliased by w-tiles) ------
    const int q   = lane >> 4;
    const int col = lane & 15;
    bf16x8 aF[4][2];
    #pragma unroll
    for (int mt = 0; mt < 4; ++mt)
        #pragma unroll
        for (int ks = 0; ks < 2; ++ks)
            aF[mt][ks] = *(const bf16x8*)(my + (mt*16 + col)*144 + q*16 + ks*64);

    // --- accumulators -------------------------------------------------------
    float out0[16], t01[8], o1b[24];
    #pragma unroll
    for (int v = 0; v < 16; ++v) out0[v] = 0.f;
    #pragma unroll
    for (int v = 0; v < 8;  ++v) t01[v]  = 0.f;
    #pragma unroll
    for (int v = 0; v < 24; ++v) o1b[v]  = 0.f;

    const bf16x8* wsBv = (const bf16x8*)wsB;
    bf16x8 bc0 = wsBv[lane];        // nt=0, ks=0
    bf16x8 bc1 = wsBv[64 + lane];   // nt=0, ks=1
    bf16x8 bn0 = {}, bn1 = {};
    float wch[16];

    // One N-tile: prefetch next B-frags, 8 MFMAs, C-tiles -> LDS (stride 20),
    // wait, read this lane's edge row (16 w values).
#define GEMM_CHUNK(NT) { \
    if ((NT) + 1 < 36) { \
        bn0 = wsBv[((NT)+1)*128 + lane]; \
        bn1 = wsBv[((NT)+1)*128 + 64 + lane]; \
    } \
    f32x4 w0 = {0.f,0.f,0.f,0.f}, w1 = {0.f,0.f,0.f,0.f}; \
    f32x4 w2 = {0.f,0.f,0.f,0.f}, w3 = {0.f,0.f,0.f,0.f}; \
    w0 = __builtin_amdgcn_mfma_f32_16x16x32_bf16(aF[0][0], bc0, w0, 0,0,0); \
    w1 = __builtin_amdgcn_mfma_f32_16x16x32_bf16(aF[1][0], bc0, w1, 0,0,0); \
    w2 = __builtin_amdgcn_mfma_f32_16x16x32_bf16(aF[2][0], bc0, w2, 0,0,0); \
    w3 = __builtin_amdgcn_mfma_f32_16x16x32_bf16(aF[3][0], bc0, w3, 0,0,0); \
    w0 = __builtin_amdgcn_mfma_f32_16x16x32_bf16(aF[0][1], bc1, w0, 0,0,0); \
    w1 = __builtin_amdgcn_mfma_f32_16x16x32_bf16(aF[1][1], bc1, w1, 0,0,0); \
    w2 = __builtin_amdgcn_mfma_f32_16x16x32_bf16(aF[2][1], bc1, w2, 0,0,0); \
    w3 = __builtin_amdgcn_mfma_f32_16x16x32_bf16(aF[3][1], bc1, w3, 0,0,0); \
    { float* wp = shf + q*80 + col; \
      wp[0]   = w0[0]; wp[20]  = w0[1]; wp[40]  = w0[2]; wp[60]  = w0[3]; \
      wp[320] = w1[0]; wp[340] = w1[1]; wp[360] = w1[2]; wp[380] = w1[3]; \
      wp[640] = w2[0]; wp[660] = w2[1]; wp[680] = w2[2]; wp[700] = w2[3]; \
      wp[960] = w3[0]; wp[980] = w3[1]; wp[1000]= w3[2]; wp[1020]= w3[3]; } \
    asm volatile("s_waitcnt lgkmcnt(0)" ::: "memory"); \
    { const float4* rp = (const float4*)(shf + lane*20); \
      float4 r0 = rp[0], r1 = rp[1], r2 = rp[2], r3 = rp[3]; \
      wch[0]=r0.x; wch[1]=r0.y; wch[2]=r0.z; wch[3]=r0.w; \
      wch[4]=r1.x; wch[5]=r1.y; wch[6]=r1.z; wch[7]=r1.w; \
      wch[8]=r2.x; wch[9]=r2.y; wch[10]=r2.z; wch[11]=r2.w; \
      wch[12]=r3.x; wch[13]=r3.y; wch[14]=r3.z; wch[15]=r3.w; } \
    bc0 = bn0; bc1 = bn1; }

    // --- path w00: tiles 0..15, out0[v] += w00[u][v] * x0[u] ---------------
    #pragma unroll
    for (int u = 0; u < 16; ++u) {
        GEMM_CHUNK(u);
        const float xv = x0[u];
        #pragma unroll
        for (int v = 0; v < 16; ++v) out0[v] = fmaf(wch[v], xv, out0[v]);
    }
    // --- path w01: tiles 16..23, t01[v] += w01[u][v] * x0[u] ---------------
    #pragma unroll
    for (int t = 0; t < 8; ++t) {
        GEMM_CHUNK(16 + t);
        const float xa = x0[2*t], xb = x0[2*t+1];
        #pragma unroll
        for (int v = 0; v < 8; ++v)
            t01[v] = fmaf(wch[v], xa, fmaf(wch[8+v], xb, t01[v]));
    }
    // --- path w10: tiles 24..27, o1b[v][k] += w10[u][v] * x1[u][k] ---------
    #pragma unroll
    for (int t = 0; t < 4; ++t) {
        GEMM_CHUNK(24 + t);
        const int u0 = 2*t;
        const float xa0 = x1[3*u0+0], xa1 = x1[3*u0+1], xa2 = x1[3*u0+2];
        const float xb0 = x1[3*u0+3], xb1 = x1[3*u0+4], xb2 = x1[3*u0+5];
        #pragma unroll
        for (int v = 0; v < 8; ++v) {
            o1b[3*v+0] = fmaf(wch[v], xa0, fmaf(wch[8+v], xb0, o1b[3*v+0]));
            o1b[3*v+1] = fmaf(wch[v], xa1, fmaf(wch[8+v], xb1, o1b[3*v+1]));
            o1b[3*v+2] = fmaf(wch[v], xa2, fmaf(wch[8+v], xb2, o1b[3*v+2]));
        }
    }
    // --- path w11: tiles 28..35, out0[v] += w11[u][v] * dot[u] -------------
    #pragma unroll
    for (int u = 0; u < 8; ++u) {
        GEMM_CHUNK(28 + u);
        const float dv = dot[u];
        #pragma unroll
        for (int v = 0; v < 16; ++v) out0[v] = fmaf(wch[v], dv, out0[v]);
    }
#undef GEMM_CHUNK

    // --- epilogue: scale, transpose through LDS, lane-contiguous atomics ---
    const float S = 1.0f / (32.0f * 4.898979485566356f);
    float fo[40];
    #pragma unroll
    for (int v = 0; v < 16; ++v) fo[v] = S * out0[v];
    #pragma unroll
    for (int v = 0; v < 8; ++v) {
        fo[16+3*v+0] = S * fmaf(t01[v], shx, o1b[3*v+0]);
        fo[16+3*v+1] = S * fmaf(t01[v], shy, o1b[3*v+1]);
        fo[16+3*v+2] = S * fmaf(t01[v], shz, o1b[3*v+2]);
    }
    {   // out-tile: stride 44 floats per edge
        float4* orow = (float4*)(shf + lane * 44);
        #pragma unroll
        for (int g = 0; g < 10; ++g)
            orow[g] = make_float4(fo[4*g], fo[4*g+1], fo[4*g+2], fo[4*g+3]);
    }
    asm volatile("s_waitcnt lgkmcnt(0)" ::: "memory");
    #pragma unroll 4
    for (int it = 0; it < 40; ++it) {
        int p  = it * 64 + lane;
        int ee = (p * 52429) >> 21;      // p / 40, exact for p < 4096
        int c  = p - ee * 40;
        float v = shf[ee * 44 + c];
        int dd = edst[wbase + ee];
        if (MODE64) {
            unsigned long long* acc = (unsigned long long*)accPtr;
            long long iv = __float2ll_rn(v * FXP64_SCALE);
            atomicAdd(acc + (size_t)dd * 40 + c, (unsigned long long)iv);
        } else {
            int* acc = (int*)accPtr;
            int iv = __float2int_rn(v * FXP32_SCALE);
            atomicAdd(acc + (size_t)dd * 40 + c, iv);
        }
    }
}

extern "C" void kernel_launch(void* const* d_in, const int* in_sizes, int n_in,
                              void* d_out, int out_size, void* d_ws, size_t ws_size,
                              hipStream_t stream) {
    const float* pos  = (const float*)d_in[0];
    const float* f_in = (const float*)d_in[1];
    const int*   esrc = (const int*)  d_in[2];
    const int*   edst = (const int*)  d_in[3];
    const float* W1   = (const float*)d_in[4];
    const float* W2   = (const float*)d_in[5];
    float* out = (float*)d_out;

    const bool use64 = ws_size >= (ACC64_BYTES + WSB_BYTES);
    const int nOut = N_NODES * 40;            // 2,000,000

    if (use64) {
        long long*      acc = (long long*)d_ws;
        unsigned short* wsB = (unsigned short*)((char*)d_ws + ACC64_BYTES);

        const int n16 = (int)(ACC64_BYTES / 16);              // 1,000,000
        zero_kernel<<<(n16 + 255) / 256, 256, 0, stream>>>((int4*)acc, n16);
        prep_w2_kernel<<<144, 256, 0, stream>>>(W2, wsB);

        conv_kernel<1><<<N_EDGES / 256, 256, 0, stream>>>(
            pos, f_in, esrc, edst, W1, wsB, (void*)acc);

        finalize64_kernel<<<(nOut + 255) / 256, 256, 0, stream>>>(acc, out, nOut);
    } else {
        // Fallback: int32 fixed point accumulated directly in d_out.
        unsigned short* wsB = (unsigned short*)d_ws;

        const int n16 = nOut / 4;                              // 500,000 int4s
        zero_kernel<<<(n16 + 255) / 256, 256, 0, stream>>>((int4*)out, n16);
        prep_w2_kernel<<<144, 256, 0, stream>>>(W2, wsB);

        conv_kernel<0><<<N_EDGES / 256, 256, 0, stream>>>(
            pos, f_in, esrc, edst, W1, wsB, (void*)out);

        finalize32_kernel<<<(n16 + 255) / 256, 256, 0, stream>>>(
            (int4*)out, (float4*)out, n16);
    }
}

// Round 4
// 308.669 us; speedup vs baseline: 1.3578x; 1.3578x over previous
//
#include <hip/hip_runtime.h>

#define N_NODES 50000
#define N_EDGES 800000

typedef short  bf16x8 __attribute__((ext_vector_type(8)));
typedef float  f32x4  __attribute__((ext_vector_type(4)));

// 64-bit fixed point (primary): scale 2^36 -> quantization 1.5e-11, range +-2^26.
#define FXP64_SCALE 68719476736.0f             // 2^36
#define FXP64_INV   1.4551915228366852e-11     // 2^-36 (double)
// 32-bit fallback (only if ws too small)
#define FXP32_SCALE 4194304.0f                 // 2^22
#define FXP32_INV   2.384185791015625e-07f     // 2^-22

#define ACC64_BYTES ((size_t)N_NODES * 40 * 8) // 16,000,000 B
#define WSB_BYTES   (36864 * 2)                // 73,728 B

__device__ __forceinline__ unsigned short f2bf(float f) {
    unsigned u = __float_as_uint(f);
    u += 0x7FFF + ((u >> 16) & 1);          // RNE
    return (unsigned short)(u >> 16);
}

__device__ __forceinline__ f32x4 fma4(f32x4 a, f32x4 b, f32x4 c) {
    f32x4 r;
    r[0] = fmaf(a[0], b[0], c[0]);
    r[1] = fmaf(a[1], b[1], c[1]);
    r[2] = fmaf(a[2], b[2], c[2]);
    r[3] = fmaf(a[3], b[3], c[3]);
    return r;
}

// ---------------------------------------------------------------------------
__global__ void zero_kernel(int4* __restrict__ p, int n16) {
    int i = blockIdx.x * blockDim.x + threadIdx.x;
    if (i < n16) p[i] = make_int4(0, 0, 0, 0);
}

__global__ void finalize64_kernel(const long long* __restrict__ acc,
                                  float* __restrict__ out, int n) {
    int i = blockIdx.x * blockDim.x + threadIdx.x;
    if (i < n) out[i] = (float)((double)acc[i] * FXP64_INV);
}

__global__ void finalize32_kernel(int4* pi, float4* pf, int n4) {
    int i = blockIdx.x * blockDim.x + threadIdx.x;
    if (i < n4) {
        int4 v = pi[i];
        float4 f;
        f.x = (float)v.x * FXP32_INV;
        f.y = (float)v.y * FXP32_INV;
        f.z = (float)v.z * FXP32_INV;
        f.w = (float)v.w * FXP32_INV;
        pf[i] = f;
    }
}

// pack W2 (64x576 f32) into bf16 B-fragment order.
// B-frag (nt,ks): lane L holds B[k=ks*32+(L>>4)*8+j][n=nt*16+(L&15)], j=0..7.
__global__ void prep_w2_kernel(const float* __restrict__ W2,
                               unsigned short* __restrict__ wsB) {
    int gid = blockIdx.x * 256 + threadIdx.x;      // 36864 total
    if (gid >= 36864) return;
    int j    = gid & 7;
    int lane = (gid >> 3) & 63;
    int ks   = (gid >> 9) & 1;
    int nt   = gid >> 10;
    int k = ks * 32 + (lane >> 4) * 8 + j;
    int n = nt * 16 + (lane & 15);
    wsB[gid] = f2bf(W2[k * 576 + n]);
}

// ---------------------------------------------------------------------------
// fused conv. Block = 256 = 4 independent waves; wave = 64 edges.
// v4 (bisection): v3's C-layout consumption + 2-phase epilogue, but the
// DENSE v2 radial-embedding/h path (bit-identical to the passing kernel).
// Explicit lgkmcnt(0) at every LDS read->overwrite transition.
// ---------------------------------------------------------------------------
template<int MODE64>
__global__ __launch_bounds__(256, 2) void conv_kernel(
    const float* __restrict__ pos,
    const float* __restrict__ f_in,
    const int*   __restrict__ esrc,
    const int*   __restrict__ edst,
    const float* __restrict__ W1,
    const unsigned short* __restrict__ wsB,
    void*        __restrict__ accPtr)
{
    // per-wave 9216 B region, reused in phases (wave-local lgkmcnt only):
    //   ph1: h-stage 64x72 bf16 (stride 144 B)          = 9216 B
    //   ph2: x0t 16x64 f32 [0,4096) + dott 8x64 [4096,6144)
    //   ph3: x1t 24x64 f32 [0,6144)
    //   ph4: E1 out0+sh+dst, stride 20 f32              = 5120 B
    //   ph5: E2 out1-fused+dst, stride 28 f32           = 7168 B
    __shared__ __align__(16) char smem[4][9216];

    const int tid  = threadIdx.x;
    const int wave = tid >> 6;
    const int lane = tid & 63;
    const int e    = blockIdx.x * 256 + tid;
    char*  my  = smem[wave];
    float* shf = (float*)my;

    const int s = esrc[e];
    const int d = edst[e];

    // early B prefetch: chunks 0 and 1
    const bf16x8* wsBv = (const bf16x8*)wsB;
    bf16x8 bc0 = wsBv[lane],        bc1 = wsBv[64 + lane];
    bf16x8 bn0 = wsBv[128 + lane],  bn1 = wsBv[192 + lane];
    bf16x8 b20, b21;

    // --- geometry -----------------------------------------------------------
    float px = pos[3*d+0] - pos[3*s+0];
    float py = pos[3*d+1] - pos[3*s+1];
    float pz = pos[3*d+2] - pos[3*s+2];
    float r  = sqrtf(px*px + py*py + pz*pz + 1e-12f);
    float inv_r = __builtin_amdgcn_rcpf(r);
    float ux = px*inv_r, uy = py*inv_r, uz = pz*inv_r;
    const float SQ3 = 1.7320508075688772f;
    float shx = SQ3*ux, shy = SQ3*uy, shz = SQ3*uz;

    // --- x = f_in[src] ------------------------------------------------------
    float x0[16], x1[24], dot[8];
    {
        const float4* xg4 = reinterpret_cast<const float4*>(f_in + (size_t)s * 40);
        float xr[40];
        #pragma unroll
        for (int q8 = 0; q8 < 10; ++q8) {
            float4 v = xg4[q8];
            xr[4*q8+0] = v.x; xr[4*q8+1] = v.y; xr[4*q8+2] = v.z; xr[4*q8+3] = v.w;
        }
        #pragma unroll
        for (int i = 0; i < 16; ++i) x0[i] = xr[i];
        #pragma unroll
        for (int i = 0; i < 24; ++i) x1[i] = xr[16+i];
        #pragma unroll
        for (int u = 0; u < 8; ++u)
            dot[u] = x1[3*u+0]*ux + x1[3*u+1]*uy + x1[3*u+2]*uz;  // = inv_s3*(x1.sh1)
    }

    // --- radial embedding (dense, identical to v2) --------------------------
    const float A = 1.14136f * 7.38905609893065f;   // 1.14136 * e^2
    const float inv_step = 17.0f / 5.0f;
    float emb[16];
    #pragma unroll
    for (int k = 0; k < 16; ++k) {
        float dd  = r * inv_step - (float)(k + 1);
        float d2v = dd * dd;
        float arg = -2.0f * __builtin_amdgcn_rcpf(1.0f - d2v);
        float val = A * __expf(arg);
        emb[k] = (d2v < 1.0f) ? val : 0.0f;
    }

    // --- h = silu(emb @ W1) (dense, identical to v2) ------------------------
    float h[64];
    #pragma unroll
    for (int i = 0; i < 64; ++i) h[i] = 0.f;
    #pragma unroll
    for (int k = 0; k < 16; ++k) {
        const float ek = emb[k];
        const float* w1row = W1 + k * 64;
        #pragma unroll
        for (int i = 0; i < 64; ++i) h[i] = fmaf(ek, w1row[i], h[i]);
    }
    #pragma unroll
    for (int i = 0; i < 64; ++i) {
        float z = h[i];
        h[i] = z * __builtin_amdgcn_rcpf(1.0f + __expf(-z));
    }

    // --- stage h -> LDS [edge][k] bf16, row stride 144 B -------------------
    {
        unsigned int hp[32];
        #pragma unroll
        for (int i = 0; i < 32; ++i)
            hp[i] = (unsigned)f2bf(h[2*i]) | ((unsigned)f2bf(h[2*i+1]) << 16);
        uint4* hrow = (uint4*)(my + lane * 144);
        #pragma unroll
        for (int g = 0; g < 8; ++g)
            hrow[g] = make_uint4(hp[4*g], hp[4*g+1], hp[4*g+2], hp[4*g+3]);
    }
    asm volatile("s_waitcnt lgkmcnt(0)" ::: "memory");

    // --- A fragments --------------------------------------------------------
    const int q   = lane >> 4;
    const int col = lane & 15;
    const int q4  = q * 4;
    const int ucol = col >> 3;     // u-parity for w01/w10 paths
    bf16x8 aF[4][2];
    #pragma unroll
    for (int mt = 0; mt < 4; ++mt)
        #pragma unroll
        for (int ks = 0; ks < 2; ++ks)
            aF[mt][ks] = *(const bf16x8*)(my + (mt*16 + col)*144 + q*16 + ks*64);
    asm volatile("s_waitcnt lgkmcnt(0)" ::: "memory");   // aF reads done before overwrite

    // --- stage x0t + dott (h region now dead) ------------------------------
    #pragma unroll
    for (int u = 0; u < 16; ++u) shf[u*64 + lane] = x0[u];
    #pragma unroll
    for (int u = 0; u < 8;  ++u) shf[1024 + u*64 + lane] = dot[u];
    asm volatile("s_waitcnt lgkmcnt(0)" ::: "memory");

    // --- distributed accumulators (C-layout: lane has edges 16mt+4q+r, col) -
    f32x4 out0d[4], t01d[4], o1bd[4][3];
    #pragma unroll
    for (int m = 0; m < 4; ++m) {
        out0d[m] = (f32x4){0.f,0.f,0.f,0.f};
        t01d[m]  = (f32x4){0.f,0.f,0.f,0.f};
        #pragma unroll
        for (int k = 0; k < 3; ++k) o1bd[m][k] = (f32x4){0.f,0.f,0.f,0.f};
    }

#define MFMA8() \
    f32x4 wr0 = {0.f,0.f,0.f,0.f}, wr1 = {0.f,0.f,0.f,0.f}; \
    f32x4 wr2 = {0.f,0.f,0.f,0.f}, wr3 = {0.f,0.f,0.f,0.f}; \
    wr0 = __builtin_amdgcn_mfma_f32_16x16x32_bf16(aF[0][0], bc0, wr0, 0,0,0); \
    wr1 = __builtin_amdgcn_mfma_f32_16x16x32_bf16(aF[1][0], bc0, wr1, 0,0,0); \
    wr2 = __builtin_amdgcn_mfma_f32_16x16x32_bf16(aF[2][0], bc0, wr2, 0,0,0); \
    wr3 = __builtin_amdgcn_mfma_f32_16x16x32_bf16(aF[3][0], bc0, wr3, 0,0,0); \
    wr0 = __builtin_amdgcn_mfma_f32_16x16x32_bf16(aF[0][1], bc1, wr0, 0,0,0); \
    wr1 = __builtin_amdgcn_mfma_f32_16x16x32_bf16(aF[1][1], bc1, wr1, 0,0,0); \
    wr2 = __builtin_amdgcn_mfma_f32_16x16x32_bf16(aF[2][1], bc1, wr2, 0,0,0); \
    wr3 = __builtin_amdgcn_mfma_f32_16x16x32_bf16(aF[3][1], bc1, wr3, 0,0,0);

#define PRE(NT2) { b20 = wsBv[(NT2)*128 + lane]; b21 = wsBv[(NT2)*128 + 64 + lane]; }
#define ROT()    { bc0 = bn0; bc1 = bn1; bn0 = b20; bn1 = b21; }

// broadcast-read 4 x f32x4 from xT row BASEW and fma into ACC[0..3]
#define CONS4(ACC, BASEW) { \
    const float* xb_ = shf + (BASEW) + q4; \
    ACC[0] = fma4(wr0, *(const f32x4*)(xb_ +  0), ACC[0]); \
    ACC[1] = fma4(wr1, *(const f32x4*)(xb_ + 16), ACC[1]); \
    ACC[2] = fma4(wr2, *(const f32x4*)(xb_ + 32), ACC[2]); \
    ACC[3] = fma4(wr3, *(const f32x4*)(xb_ + 48), ACC[3]); }

    // --- w00: chunks 0..15 (cols u*16+col) ---------------------------------
    #pragma unroll
    for (int u = 0; u < 16; ++u) {
        PRE(u + 2);                         // 2..17
        MFMA8();
        CONS4(out0d, u * 64);
        ROT();
    }
    // --- w01: chunks 16..23 (u = 2t+ucol, v = col&7) -----------------------
    #pragma unroll
    for (int t = 0; t < 8; ++t) {
        PRE(t < 6 ? 18 + t : 28 + (t - 6)); // 18..23, 28, 29
        MFMA8();
        CONS4(t01d, (2*t + ucol) * 64);
        ROT();
    }
    // resolve u-parity partials: lanes col and col^8 hold complementary sums
    #pragma unroll
    for (int m = 0; m < 4; ++m)
        #pragma unroll
        for (int rr = 0; rr < 4; ++rr)
            t01d[m][rr] += __shfl_xor(t01d[m][rr], 8);

    // --- w11: chunks 28..35 (cols u*16+col, scalar = dot) ------------------
    #pragma unroll
    for (int u = 0; u < 8; ++u) {
        PRE(u < 6 ? 30 + u : 24 + (u - 6)); // 30..35, 24, 25
        MFMA8();
        CONS4(out0d, 1024 + u * 64);
        ROT();
    }

    // --- restage x1t (x0t/dott dead); drain reads first --------------------
    asm volatile("s_waitcnt lgkmcnt(0)" ::: "memory");
    #pragma unroll
    for (int u = 0; u < 8; ++u)
        #pragma unroll
        for (int k = 0; k < 3; ++k)
            shf[(u*3 + k)*64 + lane] = x1[3*u + k];
    asm volatile("s_waitcnt lgkmcnt(0)" ::: "memory");

    // --- w10: chunks 24..27 (u = 2t+ucol, v = col&7, vector over k) --------
    #pragma unroll
    for (int t = 0; t < 4; ++t) {
        if (t < 2) PRE(26 + t);             // 26, 27
        MFMA8();
        const int ub = (2*t + ucol) * 192 + q4;
#define W10_MT(MT, WR) { \
        f32x4 xv0 = *(const f32x4*)(shf + ub +   0 + 16*(MT)); \
        f32x4 xv1 = *(const f32x4*)(shf + ub +  64 + 16*(MT)); \
        f32x4 xv2 = *(const f32x4*)(shf + ub + 128 + 16*(MT)); \
        o1bd[MT][0] = fma4(WR, xv0, o1bd[MT][0]); \
        o1bd[MT][1] = fma4(WR, xv1, o1bd[MT][1]); \
        o1bd[MT][2] = fma4(WR, xv2, o1bd[MT][2]); }
        W10_MT(0, wr0) W10_MT(1, wr1) W10_MT(2, wr2) W10_MT(3, wr3)
#undef W10_MT
        ROT();
    }
#undef CONS4
#undef PRE
#undef ROT
#undef MFMA8
    // resolve o1bd u-parity partials
    #pragma unroll
    for (int m = 0; m < 4; ++m)
        #pragma unroll
        for (int k = 0; k < 3; ++k)
            #pragma unroll
            for (int rr = 0; rr < 4; ++rr)
                o1bd[m][k][rr] += __shfl_xor(o1bd[m][k][rr], 8);

    // --- epilogue ----------------------------------------------------------
    const float FXP_S = (1.0f / (32.0f * 4.898979485566356f)) *
                        (MODE64 ? FXP64_SCALE : FXP32_SCALE);
    unsigned long long* acc64 = (unsigned long long*)accPtr;
    int*                acc32 = (int*)accPtr;

    // E1: out0 (v=col) + sh + dst, stride 20 words; drain w10 reads first
    asm volatile("s_waitcnt lgkmcnt(0)" ::: "memory");
    #pragma unroll
    for (int m = 0; m < 4; ++m)
        #pragma unroll
        for (int rr = 0; rr < 4; ++rr)
            shf[(16*m + 4*q + rr) * 20 + col] = out0d[m][rr];
    shf[lane*20 + 16] = shx;
    shf[lane*20 + 17] = shy;
    shf[lane*20 + 18] = shz;
    ((int*)shf)[lane*20 + 19] = d;
    asm volatile("s_waitcnt lgkmcnt(0)" ::: "memory");

    #pragma unroll 4
    for (int it = 0; it < 16; ++it) {
        int p  = it * 64 + lane;
        int ee = p >> 4;
        int c  = p & 15;
        float v = shf[ee*20 + c];
        int dd  = ((int*)shf)[ee*20 + 19];
        if (MODE64) {
            long long iv = __float2ll_rn(v * FXP_S);
            atomicAdd(acc64 + (size_t)dd*40 + c, (unsigned long long)iv);
        } else {
            atomicAdd(acc32 + (size_t)dd*40 + c, __float2int_rn(v * FXP_S));
        }
    }

    // E2: fused out1 = t01[v]*sh[k] + o1b[v][k], 24 words + dst, stride 28
    float shr[4][4][3];
    #pragma unroll
    for (int m = 0; m < 4; ++m)
        #pragma unroll
        for (int rr = 0; rr < 4; ++rr) {
            int eb = (16*m + 4*q + rr) * 20 + 16;
            shr[m][rr][0] = shf[eb + 0];
            shr[m][rr][1] = shf[eb + 1];
            shr[m][rr][2] = shf[eb + 2];
        }
    asm volatile("s_waitcnt lgkmcnt(0)" ::: "memory");   // shr reads done before overwrite
    if (col < 8) {
        #pragma unroll
        for (int m = 0; m < 4; ++m)
            #pragma unroll
            for (int rr = 0; rr < 4; ++rr)
                #pragma unroll
                for (int k = 0; k < 3; ++k) {
                    float fv = fmaf(t01d[m][rr], shr[m][rr][k], o1bd[m][k][rr]);
                    shf[(16*m + 4*q + rr) * 28 + 3*col + k] = fv;
                }
    }
    ((int*)shf)[lane*28 + 27] = d;
    asm volatile("s_waitcnt lgkmcnt(0)" ::: "memory");

    #pragma unroll 4
    for (int it = 0; it < 24; ++it) {
        int p  = it * 64 + lane;
        int ee = (p * 10923) >> 18;      // p / 24, exact for p < 1536
        int c  = p - ee * 24;
        float v = shf[ee*28 + c];
        int dd  = ((int*)shf)[ee*28 + 27];
        if (MODE64) {
            long long iv = __float2ll_rn(v * FXP_S);
            atomicAdd(acc64 + (size_t)dd*40 + 16 + c, (unsigned long long)iv);
        } else {
            atomicAdd(acc32 + (size_t)dd*40 + 16 + c, __float2int_rn(v * FXP_S));
        }
    }
}

extern "C" void kernel_launch(void* const* d_in, const int* in_sizes, int n_in,
                              void* d_out, int out_size, void* d_ws, size_t ws_size,
                              hipStream_t stream) {
    const float* pos  = (const float*)d_in[0];
    const float* f_in = (const float*)d_in[1];
    const int*   esrc = (const int*)  d_in[2];
    const int*   edst = (const int*)  d_in[3];
    const float* W1   = (const float*)d_in[4];
    const float* W2   = (const float*)d_in[5];
    float* out = (float*)d_out;

    const bool use64 = ws_size >= (ACC64_BYTES + WSB_BYTES);
    const int nOut = N_NODES * 40;            // 2,000,000

    if (use64) {
        long long*      acc = (long long*)d_ws;
        unsigned short* wsB = (unsigned short*)((char*)d_ws + ACC64_BYTES);

        const int n16 = (int)(ACC64_BYTES / 16);              // 1,000,000
        zero_kernel<<<(n16 + 255) / 256, 256, 0, stream>>>((int4*)acc, n16);
        prep_w2_kernel<<<144, 256, 0, stream>>>(W2, wsB);

        conv_kernel<1><<<N_EDGES / 256, 256, 0, stream>>>(
            pos, f_in, esrc, edst, W1, wsB, (void*)acc);

        finalize64_kernel<<<(nOut + 255) / 256, 256, 0, stream>>>(acc, out, nOut);
    } else {
        unsigned short* wsB = (unsigned short*)d_ws;

        const int n16 = nOut / 4;
        zero_kernel<<<(n16 + 255) / 256, 256, 0, stream>>>((int4*)out, n16);
        prep_w2_kernel<<<144, 256, 0, stream>>>(W2, wsB);

        conv_kernel<0><<<N_EDGES / 256, 256, 0, stream>>>(
            pos, f_in, esrc, edst, W1, wsB, (void*)out);

        finalize32_kernel<<<(n16 + 255) / 256, 256, 0, stream>>>(
            (int4*)out, (float4*)out, n16);
    }
}

// Round 7
// 304.522 us; speedup vs baseline: 1.3763x; 1.0136x over previous
//
#include <hip/hip_runtime.h>
#include <hip/hip_fp16.h>

#define N_NODES 50000
#define N_EDGES 800000

typedef short  bf16x8 __attribute__((ext_vector_type(8)));
typedef float  f32x4  __attribute__((ext_vector_type(4)));
typedef _Float16 h16x2 __attribute__((ext_vector_type(2)));

// 64-bit fixed point (primary): scale 2^36 -> quantization 1.5e-11, range +-2^26.
#define FXP64_SCALE 68719476736.0f             // 2^36
#define FXP64_INV   1.4551915228366852e-11     // 2^-36 (double)
// 32-bit fallback (only if ws too small)
#define FXP32_SCALE 4194304.0f                 // 2^22
#define FXP32_INV   2.384185791015625e-07f     // 2^-22

#define ACC64_BYTES ((size_t)N_NODES * 40 * 8) // 16,000,000 B
#define WSB_BYTES   (36864 * 2)                // 73,728 B
#define W1P_BYTES   (512 * 4)                  // 2,048 B (8 kk-pairs x 64 i, u32)

#if __has_builtin(__builtin_amdgcn_fdot2)
__device__ __forceinline__ float FDOT2(h16x2 a, h16x2 b, float c) {
    return __builtin_amdgcn_fdot2(a, b, c, false);
}
#else
__device__ __forceinline__ float FDOT2(h16x2 a, h16x2 b, float c) {
    return fmaf((float)a.x, (float)b.x, fmaf((float)a.y, (float)b.y, c));
}
#endif

__device__ __forceinline__ unsigned short f2bf(float f) {
    unsigned u = __float_as_uint(f);
    u += 0x7FFF + ((u >> 16) & 1);          // RNE
    return (unsigned short)(u >> 16);
}

__device__ __forceinline__ f32x4 fma4(f32x4 a, f32x4 b, f32x4 c) {
    f32x4 r;
    r[0] = fmaf(a[0], b[0], c[0]);
    r[1] = fmaf(a[1], b[1], c[1]);
    r[2] = fmaf(a[2], b[2], c[2]);
    r[3] = fmaf(a[3], b[3], c[3]);
    return r;
}

// ---------------------------------------------------------------------------
__global__ void zero_kernel(int4* __restrict__ p, int n16) {
    int i = blockIdx.x * blockDim.x + threadIdx.x;
    if (i < n16) p[i] = make_int4(0, 0, 0, 0);
}

__global__ void finalize64_kernel(const long long* __restrict__ acc,
                                  float* __restrict__ out, int n) {
    int i = blockIdx.x * blockDim.x + threadIdx.x;
    if (i < n) out[i] = (float)((double)acc[i] * FXP64_INV);
}

__global__ void finalize32_kernel(int4* pi, float4* pf, int n4) {
    int i = blockIdx.x * blockDim.x + threadIdx.x;
    if (i < n4) {
        int4 v = pi[i];
        float4 f;
        f.x = (float)v.x * FXP32_INV;
        f.y = (float)v.y * FXP32_INV;
        f.z = (float)v.z * FXP32_INV;
        f.w = (float)v.w * FXP32_INV;
        pf[i] = f;
    }
}

// pack W2 (64x576 f32) into bf16 B-fragment order, and W1 (16x64 f32) into
// f16 k-pair u32s for the dot2 h-loop: w1p[kk*64+i] = {W1[2kk][i], W1[2kk+1][i]}.
// B-frag (nt,ks): lane L holds B[k=ks*32+(L>>4)*8+j][n=nt*16+(L&15)], j=0..7.
__global__ void prep_w_kernel(const float* __restrict__ W2,
                              const float* __restrict__ W1,
                              unsigned short* __restrict__ wsB,
                              unsigned* __restrict__ w1p) {
    int gid = blockIdx.x * 256 + threadIdx.x;      // 37376 total
    if (gid < 36864) {
        int j    = gid & 7;
        int lane = (gid >> 3) & 63;
        int ks   = (gid >> 9) & 1;
        int nt   = gid >> 10;
        int k = ks * 32 + (lane >> 4) * 8 + j;
        int n = nt * 16 + (lane & 15);
        wsB[gid] = f2bf(W2[k * 576 + n]);
    } else if (gid < 36864 + 512) {
        int idx = gid - 36864;
        int kk  = idx >> 6;
        int i   = idx & 63;
        __half lo = __float2half(W1[(2*kk)     * 64 + i]);
        __half hi = __float2half(W1[(2*kk + 1) * 64 + i]);
        w1p[idx] = (unsigned)__half_as_ushort(lo)
                 | ((unsigned)__half_as_ushort(hi) << 16);
    }
}

// ---------------------------------------------------------------------------
// fused conv. Block = 256 = 4 independent waves; wave = 64 edges.
// v7 = v4 (verified: dense emb, C-layout consumption, full lgkmcnt drains at
// every LDS read->overwrite transition) + f16 dot2 h-loop: h accumulated via
// v_dot2_f32_f16 against f16-packed W1 (512 dot2 vs 1024 f32 fma). emb[16]
// itself is the UNCHANGED dense path (sparse bucket selection is abandoned:
// empirically toxic, absmax 0.3047 across 3 variants).
// ---------------------------------------------------------------------------
template<int MODE64>
__global__ __launch_bounds__(256, 2) void conv_kernel(
    const float* __restrict__ pos,
    const float* __restrict__ f_in,
    const int*   __restrict__ esrc,
    const int*   __restrict__ edst,
    const unsigned* __restrict__ w1p,
    const unsigned short* __restrict__ wsB,
    void*        __restrict__ accPtr)
{
    // per-wave 9216 B region, reused in phases (wave-local lgkmcnt only):
    //   ph1: h-stage 64x72 bf16 (stride 144 B)          = 9216 B
    //   ph2: x0t 16x64 f32 [0,4096) + dott 8x64 [4096,6144)
    //   ph3: x1t 24x64 f32 [0,6144)
    //   ph4: E1 out0+sh+dst, stride 20 f32              = 5120 B
    //   ph5: E2 out1-fused+dst, stride 28 f32           = 7168 B
    __shared__ __align__(16) char smem[4][9216];

    const int tid  = threadIdx.x;
    const int wave = tid >> 6;
    const int lane = tid & 63;
    const int e    = blockIdx.x * 256 + tid;
    char*  my  = smem[wave];
    float* shf = (float*)my;

    const int s = esrc[e];
    const int d = edst[e];

    // early B prefetch: chunks 0 and 1
    const bf16x8* wsBv = (const bf16x8*)wsB;
    bf16x8 bc0 = wsBv[lane],        bc1 = wsBv[64 + lane];
    bf16x8 bn0 = wsBv[128 + lane],  bn1 = wsBv[192 + lane];
    bf16x8 b20, b21;

    // --- geometry -----------------------------------------------------------
    float px = pos[3*d+0] - pos[3*s+0];
    float py = pos[3*d+1] - pos[3*s+1];
    float pz = pos[3*d+2] - pos[3*s+2];
    float r  = sqrtf(px*px + py*py + pz*pz + 1e-12f);
    float inv_r = __builtin_amdgcn_rcpf(r);
    float ux = px*inv_r, uy = py*inv_r, uz = pz*inv_r;
    const float SQ3 = 1.7320508075688772f;
    float shx = SQ3*ux, shy = SQ3*uy, shz = SQ3*uz;

    // --- x = f_in[src] ------------------------------------------------------
    float x0[16], x1[24], dot[8];
    {
        const float4* xg4 = reinterpret_cast<const float4*>(f_in + (size_t)s * 40);
        float xr[40];
        #pragma unroll
        for (int q8 = 0; q8 < 10; ++q8) {
            float4 v = xg4[q8];
            xr[4*q8+0] = v.x; xr[4*q8+1] = v.y; xr[4*q8+2] = v.z; xr[4*q8+3] = v.w;
        }
        #pragma unroll
        for (int i = 0; i < 16; ++i) x0[i] = xr[i];
        #pragma unroll
        for (int i = 0; i < 24; ++i) x1[i] = xr[16+i];
        #pragma unroll
        for (int u = 0; u < 8; ++u)
            dot[u] = x1[3*u+0]*ux + x1[3*u+1]*uy + x1[3*u+2]*uz;  // = inv_s3*(x1.sh1)
    }

    // --- radial embedding (dense, verified) ---------------------------------
    const float A = 1.14136f * 7.38905609893065f;   // 1.14136 * e^2
    const float inv_step = 17.0f / 5.0f;
    float emb[16];
    #pragma unroll
    for (int k = 0; k < 16; ++k) {
        float dd  = r * inv_step - (float)(k + 1);
        float d2v = dd * dd;
        float arg = -2.0f * __builtin_amdgcn_rcpf(1.0f - d2v);
        float val = A * __expf(arg);
        emb[k] = (d2v < 1.0f) ? val : 0.0f;
    }

    // --- h = silu(emb @ W1) via f16 dot2 ------------------------------------
    // emb packed to f16 k-pairs in-register; W1 pre-packed (w1p, uniform
    // address -> scalar loads). f16 error (2^-11 rel) < bf16 rounding that h
    // receives anyway for the MFMA A-fragments.
    unsigned ep[8];
    #pragma unroll
    for (int kk = 0; kk < 8; ++kk) {
        __half lo = __float2half(emb[2*kk]);
        __half hi = __float2half(emb[2*kk+1]);
        ep[kk] = (unsigned)__half_as_ushort(lo)
               | ((unsigned)__half_as_ushort(hi) << 16);
    }
    float h[64];
    #pragma unroll
    for (int i = 0; i < 64; ++i) h[i] = 0.f;
    #pragma unroll
    for (int kk = 0; kk < 8; ++kk) {
        h16x2 ev = __builtin_bit_cast(h16x2, ep[kk]);
        const unsigned* wrow = w1p + kk * 64;
        #pragma unroll
        for (int i = 0; i < 64; ++i) {
            h16x2 wv = __builtin_bit_cast(h16x2, wrow[i]);
            h[i] = FDOT2(ev, wv, h[i]);
        }
    }
    #pragma unroll
    for (int i = 0; i < 64; ++i) {
        float z = h[i];
        h[i] = z * __builtin_amdgcn_rcpf(1.0f + __expf(-z));
    }

    // --- stage h -> LDS [edge][k] bf16, row stride 144 B -------------------
    {
        unsigned int hp[32];
        #pragma unroll
        for (int i = 0; i < 32; ++i)
            hp[i] = (unsigned)f2bf(h[2*i]) | ((unsigned)f2bf(h[2*i+1]) << 16);
        uint4* hrow = (uint4*)(my + lane * 144);
        #pragma unroll
        for (int g = 0; g < 8; ++g)
            hrow[g] = make_uint4(hp[4*g], hp[4*g+1], hp[4*g+2], hp[4*g+3]);
    }
    asm volatile("s_waitcnt lgkmcnt(0)" ::: "memory");

    // --- A fragments --------------------------------------------------------
    const int q   = lane >> 4;
    const int col = lane & 15;
    const int q4  = q * 4;
    const int ucol = col >> 3;     // u-parity for w01/w10 paths
    bf16x8 aF[4][2];
    #pragma unroll
    for (int mt = 0; mt < 4; ++mt)
        #pragma unroll
        for (int ks = 0; ks < 2; ++ks)
            aF[mt][ks] = *(const bf16x8*)(my + (mt*16 + col)*144 + q*16 + ks*64);
    asm volatile("s_waitcnt lgkmcnt(0)" ::: "memory");   // aF reads done before overwrite

    // --- stage x0t + dott (h region now dead) ------------------------------
    #pragma unroll
    for (int u = 0; u < 16; ++u) shf[u*64 + lane] = x0[u];
    #pragma unroll
    for (int u = 0; u < 8;  ++u) shf[1024 + u*64 + lane] = dot[u];
    asm volatile("s_waitcnt lgkmcnt(0)" ::: "memory");

    // --- distributed accumulators (C-layout: lane has edges 16mt+4q+r, col) -
    f32x4 out0d[4], t01d[4], o1bd[4][3];
    #pragma unroll
    for (int m = 0; m < 4; ++m) {
        out0d[m] = (f32x4){0.f,0.f,0.f,0.f};
        t01d[m]  = (f32x4){0.f,0.f,0.f,0.f};
        #pragma unroll
        for (int k = 0; k < 3; ++k) o1bd[m][k] = (f32x4){0.f,0.f,0.f,0.f};
    }

#define MFMA8() \
    f32x4 wr0 = {0.f,0.f,0.f,0.f}, wr1 = {0.f,0.f,0.f,0.f}; \
    f32x4 wr2 = {0.f,0.f,0.f,0.f}, wr3 = {0.f,0.f,0.f,0.f}; \
    wr0 = __builtin_amdgcn_mfma_f32_16x16x32_bf16(aF[0][0], bc0, wr0, 0,0,0); \
    wr1 = __builtin_amdgcn_mfma_f32_16x16x32_bf16(aF[1][0], bc0, wr1, 0,0,0); \
    wr2 = __builtin_amdgcn_mfma_f32_16x16x32_bf16(aF[2][0], bc0, wr2, 0,0,0); \
    wr3 = __builtin_amdgcn_mfma_f32_16x16x32_bf16(aF[3][0], bc0, wr3, 0,0,0); \
    wr0 = __builtin_amdgcn_mfma_f32_16x16x32_bf16(aF[0][1], bc1, wr0, 0,0,0); \
    wr1 = __builtin_amdgcn_mfma_f32_16x16x32_bf16(aF[1][1], bc1, wr1, 0,0,0); \
    wr2 = __builtin_amdgcn_mfma_f32_16x16x32_bf16(aF[2][1], bc1, wr2, 0,0,0); \
    wr3 = __builtin_amdgcn_mfma_f32_16x16x32_bf16(aF[3][1], bc1, wr3, 0,0,0);

#define PRE(NT2) { b20 = wsBv[(NT2)*128 + lane]; b21 = wsBv[(NT2)*128 + 64 + lane]; }
#define ROT()    { bc0 = bn0; bc1 = bn1; bn0 = b20; bn1 = b21; }

// broadcast-read 4 x f32x4 from xT row BASEW and fma into ACC[0..3]
#define CONS4(ACC, BASEW) { \
    const float* xb_ = shf + (BASEW) + q4; \
    ACC[0] = fma4(wr0, *(const f32x4*)(xb_ +  0), ACC[0]); \
    ACC[1] = fma4(wr1, *(const f32x4*)(xb_ + 16), ACC[1]); \
    ACC[2] = fma4(wr2, *(const f32x4*)(xb_ + 32), ACC[2]); \
    ACC[3] = fma4(wr3, *(const f32x4*)(xb_ + 48), ACC[3]); }

    // --- w00: chunks 0..15 (cols u*16+col) ---------------------------------
    #pragma unroll
    for (int u = 0; u < 16; ++u) {
        PRE(u + 2);                         // 2..17
        MFMA8();
        CONS4(out0d, u * 64);
        ROT();
    }
    // --- w01: chunks 16..23 (u = 2t+ucol, v = col&7) -----------------------
    #pragma unroll
    for (int t = 0; t < 8; ++t) {
        PRE(t < 6 ? 18 + t : 28 + (t - 6)); // 18..23, 28, 29
        MFMA8();
        CONS4(t01d, (2*t + ucol) * 64);
        ROT();
    }
    // resolve u-parity partials: lanes col and col^8 hold complementary sums
    #pragma unroll
    for (int m = 0; m < 4; ++m)
        #pragma unroll
        for (int rr = 0; rr < 4; ++rr)
            t01d[m][rr] += __shfl_xor(t01d[m][rr], 8);

    // --- w11: chunks 28..35 (cols u*16+col, scalar = dot) ------------------
    #pragma unroll
    for (int u = 0; u < 8; ++u) {
        PRE(u < 6 ? 30 + u : 24 + (u - 6)); // 30..35, 24, 25
        MFMA8();
        CONS4(out0d, 1024 + u * 64);
        ROT();
    }

    // --- restage x1t (x0t/dott dead); drain reads first --------------------
    asm volatile("s_waitcnt lgkmcnt(0)" ::: "memory");
    #pragma unroll
    for (int u = 0; u < 8; ++u)
        #pragma unroll
        for (int k = 0; k < 3; ++k)
            shf[(u*3 + k)*64 + lane] = x1[3*u + k];
    asm volatile("s_waitcnt lgkmcnt(0)" ::: "memory");

    // --- w10: chunks 24..27 (u = 2t+ucol, v = col&7, vector over k) --------
    #pragma unroll
    for (int t = 0; t < 4; ++t) {
        if (t < 2) PRE(26 + t);             // 26, 27
        MFMA8();
        const int ub = (2*t + ucol) * 192 + q4;
#define W10_MT(MT, WR) { \
        f32x4 xv0 = *(const f32x4*)(shf + ub +   0 + 16*(MT)); \
        f32x4 xv1 = *(const f32x4*)(shf + ub +  64 + 16*(MT)); \
        f32x4 xv2 = *(const f32x4*)(shf + ub + 128 + 16*(MT)); \
        o1bd[MT][0] = fma4(WR, xv0, o1bd[MT][0]); \
        o1bd[MT][1] = fma4(WR, xv1, o1bd[MT][1]); \
        o1bd[MT][2] = fma4(WR, xv2, o1bd[MT][2]); }
        W10_MT(0, wr0) W10_MT(1, wr1) W10_MT(2, wr2) W10_MT(3, wr3)
#undef W10_MT
        ROT();
    }
#undef CONS4
#undef PRE
#undef ROT
#undef MFMA8
    // resolve o1bd u-parity partials
    #pragma unroll
    for (int m = 0; m < 4; ++m)
        #pragma unroll
        for (int k = 0; k < 3; ++k)
            #pragma unroll
            for (int rr = 0; rr < 4; ++rr)
                o1bd[m][k][rr] += __shfl_xor(o1bd[m][k][rr], 8);

    // --- epilogue ----------------------------------------------------------
    const float FXP_S = (1.0f / (32.0f * 4.898979485566356f)) *
                        (MODE64 ? FXP64_SCALE : FXP32_SCALE);
    unsigned long long* acc64 = (unsigned long long*)accPtr;
    int*                acc32 = (int*)accPtr;

    // E1: out0 (v=col) + sh + dst, stride 20 words; drain w10 reads first
    asm volatile("s_waitcnt lgkmcnt(0)" ::: "memory");
    #pragma unroll
    for (int m = 0; m < 4; ++m)
        #pragma unroll
        for (int rr = 0; rr < 4; ++rr)
            shf[(16*m + 4*q + rr) * 20 + col] = out0d[m][rr];
    shf[lane*20 + 16] = shx;
    shf[lane*20 + 17] = shy;
    shf[lane*20 + 18] = shz;
    ((int*)shf)[lane*20 + 19] = d;
    asm volatile("s_waitcnt lgkmcnt(0)" ::: "memory");

    #pragma unroll 4
    for (int it = 0; it < 16; ++it) {
        int p  = it * 64 + lane;
        int ee = p >> 4;
        int c  = p & 15;
        float v = shf[ee*20 + c];
        int dd  = ((int*)shf)[ee*20 + 19];
        if (MODE64) {
            long long iv = __float2ll_rn(v * FXP_S);
            atomicAdd(acc64 + (size_t)dd*40 + c, (unsigned long long)iv);
        } else {
            atomicAdd(acc32 + (size_t)dd*40 + c, __float2int_rn(v * FXP_S));
        }
    }

    // E2: fused out1 = t01[v]*sh[k] + o1b[v][k], 24 words + dst, stride 28
    float shr[4][4][3];
    #pragma unroll
    for (int m = 0; m < 4; ++m)
        #pragma unroll
        for (int rr = 0; rr < 4; ++rr) {
            int eb = (16*m + 4*q + rr) * 20 + 16;
            shr[m][rr][0] = shf[eb + 0];
            shr[m][rr][1] = shf[eb + 1];
            shr[m][rr][2] = shf[eb + 2];
        }
    asm volatile("s_waitcnt lgkmcnt(0)" ::: "memory");   // shr reads done before overwrite
    if (col < 8) {
        #pragma unroll
        for (int m = 0; m < 4; ++m)
            #pragma unroll
            for (int rr = 0; rr < 4; ++rr)
                #pragma unroll
                for (int k = 0; k < 3; ++k) {
                    float fv = fmaf(t01d[m][rr], shr[m][rr][k], o1bd[m][k][rr]);
                    shf[(16*m + 4*q + rr) * 28 + 3*col + k] = fv;
                }
    }
    ((int*)shf)[lane*28 + 27] = d;
    asm volatile("s_waitcnt lgkmcnt(0)" ::: "memory");

    #pragma unroll 4
    for (int it = 0; it < 24; ++it) {
        int p  = it * 64 + lane;
        int ee = (p * 10923) >> 18;      // p / 24, exact for p < 1536
        int c  = p - ee * 24;
        float v = shf[ee*28 + c];
        int dd  = ((int*)shf)[ee*28 + 27];
        if (MODE64) {
            long long iv = __float2ll_rn(v * FXP_S);
            atomicAdd(acc64 + (size_t)dd*40 + 16 + c, (unsigned long long)iv);
        } else {
            atomicAdd(acc32 + (size_t)dd*40 + 16 + c, __float2int_rn(v * FXP_S));
        }
    }
}

extern "C" void kernel_launch(void* const* d_in, const int* in_sizes, int n_in,
                              void* d_out, int out_size, void* d_ws, size_t ws_size,
                              hipStream_t stream) {
    const float* pos  = (const float*)d_in[0];
    const float* f_in = (const float*)d_in[1];
    const int*   esrc = (const int*)  d_in[2];
    const int*   edst = (const int*)  d_in[3];
    const float* W1   = (const float*)d_in[4];
    const float* W2   = (const float*)d_in[5];
    float* out = (float*)d_out;

    const bool use64 = ws_size >= (ACC64_BYTES + WSB_BYTES + W1P_BYTES);
    const int nOut = N_NODES * 40;            // 2,000,000

    if (use64) {
        long long*      acc = (long long*)d_ws;
        unsigned short* wsB = (unsigned short*)((char*)d_ws + ACC64_BYTES);
        unsigned*       w1p = (unsigned*)((char*)d_ws + ACC64_BYTES + WSB_BYTES);

        const int n16 = (int)(ACC64_BYTES / 16);              // 1,000,000
        zero_kernel<<<(n16 + 255) / 256, 256, 0, stream>>>((int4*)acc, n16);
        prep_w_kernel<<<146, 256, 0, stream>>>(W2, W1, wsB, w1p);

        conv_kernel<1><<<N_EDGES / 256, 256, 0, stream>>>(
            pos, f_in, esrc, edst, w1p, wsB, (void*)acc);

        finalize64_kernel<<<(nOut + 255) / 256, 256, 0, stream>>>(acc, out, nOut);
    } else {
        unsigned short* wsB = (unsigned short*)d_ws;
        unsigned*       w1p = (unsigned*)((char*)d_ws + WSB_BYTES);

        const int n16 = nOut / 4;
        zero_kernel<<<(n16 + 255) / 256, 256, 0, stream>>>((int4*)out, n16);
        prep_w_kernel<<<146, 256, 0, stream>>>(W2, W1, wsB, w1p);

        conv_kernel<0><<<N_EDGES / 256, 256, 0, stream>>>(
            pos, f_in, esrc, edst, w1p, wsB, (void*)out);

        finalize32_kernel<<<(n16 + 255) / 256, 256, 0, stream>>>(
            (int4*)out, (float4*)out, n16);
    }
}